// Round 3
// baseline (43.384 us; speedup 1.0000x reference)
//
#include <hip/hip_runtime.h>

// WideModel: 8 hashed multi-hot features + sparse linear combine.
// Strategy: one WAVE per (row, feature). Lane i holds element i (coalesced
// 200 B load per wave), mod by compile-time bucket, dedupe via wave-private
// 128-slot LDS hash set (atomicCAS insert-if-absent), gather W for winning
// lanes, shfl_xor reduce, one atomicAdd per wave into bias-initialized out.

constexpr int B = 16384;
constexpr int L = 50;
constexpr int SLOTS = 128;   // >= 2x max inserts (50) -> short probe chains

struct KArgs {
    const int*   x[8];
    const float* w[8];
    const float* bias;
    float*       out;
};

__global__ __launch_bounds__(256) void wide_wave_kernel(KArgs a) {
    __shared__ unsigned tbl[4][SLOTS];          // one table per wave

    const int wave = threadIdx.x >> 6;
    const int lane = threadIdx.x & 63;
    const int feat = blockIdx.x >> 12;          // 4096 blocks per feature
    const int row  = ((blockIdx.x & 4095) << 2) | wave;

    // zero this wave's table (2 slots per lane)
    tbl[wave][lane]      = 0u;
    tbl[wave][lane + 64] = 0u;
    __syncthreads();  // order zero-stores before CAS probes

    // coalesced load: lane i -> element i of the row
    int v = -1;
    if (lane < L) v = a.x[feat][row * L + lane];
    const bool valid = (v >= 0);

    unsigned bin;
    if (feat < 6) bin = (unsigned)v % 100000u;   // compile-time magic-mul
    else          bin = (unsigned)v % 1000000u;

    // insert-if-absent: exactly one lane per distinct bin gets keep=true
    bool keep = false;
    if (valid) {
        const unsigned key = bin + 1u;           // 0 = empty sentinel
        unsigned h = (bin * 2654435761u) >> 25;  // top 7 bits -> [0,128)
        for (;;) {
            unsigned cur = atomicCAS(&tbl[wave][h], 0u, key);
            if (cur == 0u) { keep = true; break; }  // inserted
            if (cur == key) break;                   // duplicate
            h = (h + 1) & (SLOTS - 1);               // collision: next slot
        }
    }

    // gather + wave reduction
    float acc = keep ? a.w[feat][bin] : 0.0f;
    #pragma unroll
    for (int off = 32; off; off >>= 1)
        acc += __shfl_xor(acc, off);

    if (lane == 0) atomicAdd(&a.out[row], acc);
}

__global__ __launch_bounds__(256) void init_kernel(float* out, const float* bias) {
    const int i = blockIdx.x * 256 + (int)threadIdx.x;
    out[i] = bias[0];
}

extern "C" void kernel_launch(void* const* d_in, const int* in_sizes, int n_in,
                              void* d_out, int out_size, void* d_ws, size_t ws_size,
                              hipStream_t stream) {
    KArgs a;
    for (int i = 0; i < 8; ++i) a.x[i] = (const int*)d_in[i];
    for (int i = 0; i < 8; ++i) a.w[i] = (const float*)d_in[8 + i];
    a.bias = (const float*)d_in[16];
    a.out  = (float*)d_out;

    init_kernel<<<B / 256, 256, 0, stream>>>(a.out, a.bias);
    wide_wave_kernel<<<8 * (B / 4), 256, 0, stream>>>(a);
}